// Round 8
// baseline (138.925 us; speedup 1.0000x reference)
//
#include <hip/hip_runtime.h>
#include <hip/hip_bf16.h>
#include <cstdint>

// TT-linear: y[4096,4096] = x[4096,1024] @ W[1024,4096] + bias
// Kernel 1 (prep): fused x->bf16 convert + W^T reconstruction from TT cores (unchanged).
// Kernel 2 (tt_gemm): Round-8 = R7 skeleton (256x256, BK=64, 8 waves 2Mx4N,
//   2 barriers/K-tile, counted vmcnt(4), XOR-swizzled LDS) with:
//   (a) 32x32x16 MFMA (2495 vs 2075 TF ceiling; half the instructions);
//   (b) ks1 frag reads hoisted above the ks0 MFMA cluster so LDS-read time
//       hides under matrix-pipe time (R0-R7 all showed read/MFMA SERIAL:
//       5300 cyc/tile ~ 2480 MFMA + 2300 LDS reads + stage, the serial sum).
//   Hazard ledger identical to R7: at tile kt start the WHOLE tile is in LDS
//   (E1/E2(kt-1)=ks1 and E3/E4(kt-2)=ks0 both certified by vmcnt(4)+BAR);
//   mid-BAR protects same-slot ks0 staging (ks0 reads retired via the
//   compiler's lgkm waits on the ks0 MFMAs before any wave reaches it).

typedef __bf16 bf16x8 __attribute__((ext_vector_type(8)));
typedef float f32x4 __attribute__((ext_vector_type(4)));
typedef float f32x16 __attribute__((ext_vector_type(16)));

__device__ __forceinline__ void g2lds16(const void* g, void* l) {
    __builtin_amdgcn_global_load_lds(
        (const __attribute__((address_space(1))) void*)g,
        (__attribute__((address_space(3))) void*)l,
        16, 0, 0);
}

// --------------------------------------------------------------------- prep
__global__ __launch_bounds__(256) void prep(
    const float* __restrict__ x, __bf16* __restrict__ xb,
    const float* __restrict__ c0, const float* __restrict__ c1,
    const float* __restrict__ c2, const float* __restrict__ c3,
    __bf16* __restrict__ wt) {
    const int b = blockIdx.x;
    const int t = threadIdx.x;
    if (b < 2048) {
        const int i = (b * 256 + t) * 8;
        float4 a0 = *(const float4*)(x + i);
        float4 a1 = *(const float4*)(x + i + 4);
        bf16x8 o;
        o[0] = (__bf16)a0.x; o[1] = (__bf16)a0.y; o[2] = (__bf16)a0.z; o[3] = (__bf16)a0.w;
        o[4] = (__bf16)a1.x; o[5] = (__bf16)a1.y; o[6] = (__bf16)a1.z; o[7] = (__bf16)a1.w;
        *(bf16x8*)(xb + i) = o;
        return;
    }
    __shared__ float t12[4][16];     // [wave][r2]
    __shared__ float t123[4][512];   // [wave][m3*8+n3][r3]
    __shared__ float c3s[512];       // [(r3*4+m4)*8+n4]
    #pragma unroll
    for (int i = t; i < 512; i += 256) c3s[i] = c3[i];
    const int s = t >> 6;
    const int lane = t & 63;
    const int g = (b - 2048) * 4 + s;
    const int m1 = g >> 9, n1 = (g >> 6) & 7, m2 = (g >> 3) & 7, n2 = g & 7;
    __syncthreads();
    if (lane < 16) {
        const int r2 = lane;
        float sum = 0.f;
        #pragma unroll
        for (int r1 = 0; r1 < 16; ++r1)
            sum += c0[(m1 * 8 + n1) * 16 + r1] * c1[((r1 * 8 + m2) * 8 + n2) * 16 + r2];
        t12[s][r2] = sum;
    }
    __syncthreads();
    #pragma unroll
    for (int idx = lane; idx < 512; idx += 64) {
        const int m3 = idx >> 7, n3 = (idx >> 4) & 7, r3 = idx & 15;
        float sum = 0.f;
        #pragma unroll
        for (int r2 = 0; r2 < 16; ++r2)
            sum += t12[s][r2] * c2[((r2 * 4 + m3) * 8 + n3) * 16 + r3];
        t123[s][(m3 * 8 + n3) * 16 + r3] = sum;
    }
    __syncthreads();
    const int n3 = lane >> 3, n4 = lane & 7;
    const int n = ((n1 * 8 + n2) * 8 + n3) * 8 + n4;
    const int kbase = (m1 * 8 + m2) * 16;
    float v[16];
    #pragma unroll
    for (int e = 0; e < 16; ++e) v[e] = 0.f;
    #pragma unroll
    for (int m3 = 0; m3 < 4; ++m3) {
        #pragma unroll
        for (int r3 = 0; r3 < 16; ++r3) {
            const float tv = t123[s][(m3 * 8 + n3) * 16 + r3];
            #pragma unroll
            for (int m4 = 0; m4 < 4; ++m4)
                v[m3 * 4 + m4] += tv * c3s[(r3 * 4 + m4) * 8 + n4];
        }
    }
    bf16x8 lo, hi;
    #pragma unroll
    for (int e = 0; e < 8; ++e) { lo[e] = (__bf16)v[e]; hi[e] = (__bf16)v[8 + e]; }
    *(bf16x8*)(wt + (size_t)n * 1024 + kbase)     = lo;
    *(bf16x8*)(wt + (size_t)n * 1024 + kbase + 8) = hi;
}

// -------------------------------------------------------------- GEMM + bias
// C[4096,4096] f32 = A[4096,1024] bf16 @ Bt[4096,1024]^T bf16 + bias
// Geometry: BM=BN=256, BK=64 (16 K-tiles), 8 waves 2Mx4N (wave 128x64),
// 512 threads, grid 256. LDS sA/sB[2 slots][2 ks][256x32] = 128 KB.
// MFMA 32x32x16: per ks-half per wave: A 4mi x 2kk, B 2ni x 2kk frags (12
// b128 reads), 16 MFMA. C/D: col=lane&31, row=(reg&3)+8*(reg>>2)+4*(lane>>5).
// Swizzle: 64-B rows, 4 x 16B chunks, phys = logical ^ ((row>>1)&3) on both
// staging-source and read sides. 32x32 frag read: row = base+mi*32+(l&31),
// chunk = (kk*2 + (lane>>5)) ^ ((l31>>1)&3) -> 8-lane batches hit 8 distinct
// bank quads (0 conflicts, same involution as R5/R7).

#define SCHED() __builtin_amdgcn_sched_barrier(0)
#define BAR()  do { SCHED(); __builtin_amdgcn_s_barrier(); SCHED(); } while (0)
#define WAITVM(n) do { SCHED(); asm volatile("s_waitcnt vmcnt(" #n ")"); SCHED(); } while (0)

__global__ __launch_bounds__(512, 2) void tt_gemm(
    const __bf16* __restrict__ A, const __bf16* __restrict__ B,
    const float* __restrict__ bias, float* __restrict__ C) {
    constexpr int K = 1024, N = 4096;
    constexpr int NKT = 16;                  // K-tiles of 64
    __shared__ __bf16 sA[2][2][256 * 32];    // [slot][ks][16 KB]
    __shared__ __bf16 sB[2][2][256 * 32];
    const int t = threadIdx.x;
    const int lane = t & 63;
    const int wave = t >> 6;                 // 0..7
    const int wm = (wave >> 2) * 128;        // 0 / 128   (M range of wave)
    const int wn = (wave & 3) * 64;          // 0..192    (N range of wave)
    const int l31 = lane & 31, lk = lane >> 5;
    // swizzled byte offset of (kk) sub-chunk for this lane's row (l31)
    const int key = (l31 >> 1) & 3;
    const int cO0 = ((0 * 2 + lk) ^ key) << 4;   // kk=0
    const int cO1 = ((1 * 2 + lk) ^ key) << 4;   // kk=1

    // XCD-aware mapping: each XCD owns an 8m x 4n rectangle of 256-tiles
    const int xcd = blockIdx.x & 7;
    const int lid = blockIdx.x >> 3;         // 0..31
    const int bm = ((xcd >> 2) * 8 + (lid & 7)) * 256;
    const int bn = ((xcd & 3) * 4 + (lid >> 3)) * 256;

    // staging: 16-KB ks-half = 1024 chunks of 16B; thread owns c = t, t+512
    const int c0i = t, c1i = t + 512;
    const int r0 = c0i >> 2, r1 = c1i >> 2;              // row in tile 0..255
    const int lc0 = (c0i & 3) ^ ((r0 >> 1) & 3);         // logical chunk (global)
    const int lc1 = (c1i & 3) ^ ((r1 >> 1) & 3);
    const __bf16* a0p = A + (size_t)(bm + r0) * K + lc0 * 8;
    const __bf16* a1p = A + (size_t)(bm + r1) * K + lc1 * 8;
    const __bf16* b0p = B + (size_t)(bn + r0) * K + lc0 * 8;
    const __bf16* b1p = B + (size_t)(bn + r1) * K + lc1 * 8;

#define ST_A(kt, ks) do { \
    g2lds16(a0p + (size_t)(kt) * 64 + (ks) * 32, (char*)&sA[(kt) & 1][ks][0] + c0i * 16); \
    g2lds16(a1p + (size_t)(kt) * 64 + (ks) * 32, (char*)&sA[(kt) & 1][ks][0] + c1i * 16); } while (0)
#define ST_B(kt, ks) do { \
    g2lds16(b0p + (size_t)(kt) * 64 + (ks) * 32, (char*)&sB[(kt) & 1][ks][0] + c0i * 16); \
    g2lds16(b1p + (size_t)(kt) * 64 + (ks) * 32, (char*)&sB[(kt) & 1][ks][0] + c1i * 16); } while (0)
// 32x32 fragment loads (kk selects K-sub-16 inside the 32-k half)
#define LDA32(dst, mi, kk, ks) dst = *(const bf16x8*)((const char*)&sA[slot][ks][0] \
    + (wm + (mi) * 32 + l31) * 64 + ((kk) ? cO1 : cO0))
#define LDB32(dst, ni, kk, ks) dst = *(const bf16x8*)((const char*)&sB[slot][ks][0] \
    + (wn + (ni) * 32 + l31) * 64 + ((kk) ? cO1 : cO0))
// 16 MFMA 32x32x16 for one ks-half: a[4][2], b[2][2]
#define MFMA_HALF(a, b) do { \
    __builtin_amdgcn_s_setprio(1); \
    _Pragma("unroll") \
    for (int kk = 0; kk < 2; ++kk) \
        _Pragma("unroll") \
        for (int mi = 0; mi < 4; ++mi) \
            _Pragma("unroll") \
            for (int ni = 0; ni < 2; ++ni) \
                acc[mi][ni] = __builtin_amdgcn_mfma_f32_32x32x16_bf16( \
                    a[mi][kk], b[ni][kk], acc[mi][ni], 0, 0, 0); \
    __builtin_amdgcn_s_setprio(0); } while (0)

    f32x16 acc[4][2] = {};

    // prologue: 12 loads; WAITVM(4) -> oldest 8 done = tile0 BOTH halves present
    ST_A(0, 0); ST_B(0, 0);
    ST_A(0, 1); ST_B(0, 1);
    ST_A(1, 0); ST_B(1, 0);
    WAITVM(4);
    BAR();

    #pragma unroll 1
    for (int kt = 0; kt < NKT; ++kt) {
        const int slot = kt & 1;
        bf16x8 a0f[4][2], b0f[2][2], a1f[4][2], b1f[2][2];
        // ---- ks0 reads (12)
        #pragma unroll
        for (int mi = 0; mi < 4; ++mi) { LDA32(a0f[mi][0], mi, 0, 0); LDA32(a0f[mi][1], mi, 1, 0); }
        #pragma unroll
        for (int ni = 0; ni < 2; ++ni) { LDB32(b0f[ni][0], ni, 0, 0); LDB32(b0f[ni][1], ni, 1, 0); }
        // ---- hoisted ks1 reads (8 of 12): hide under ks0 MFMA
        #pragma unroll
        for (int ni = 0; ni < 2; ++ni) { LDB32(b1f[ni][0], ni, 0, 1); LDB32(b1f[ni][1], ni, 1, 1); }
        #pragma unroll
        for (int mi = 0; mi < 4; ++mi) LDA32(a1f[mi][0], mi, 0, 1);
        if (kt < NKT - 1) { ST_A(kt + 1, 1); ST_B(kt + 1, 1); }   // E1/E2
        MFMA_HALF(a0f, b0f);
        BAR();   // ks0 reads retired (lgkm waits on ks0 MFMAs) -> ks0 staging safe
        // ---- remaining ks1 reads (4) + E3/E4 stage + ks1 MFMA
        #pragma unroll
        for (int mi = 0; mi < 4; ++mi) LDA32(a1f[mi][1], mi, 1, 1);
        if (kt < NKT - 2) { ST_A(kt + 2, 0); ST_B(kt + 2, 0); }   // E3/E4
        MFMA_HALF(a1f, b1f);
        if (kt < NKT - 2)       { WAITVM(4); }   // certifies kt+1 both halves
        else if (kt == NKT - 2) { WAITVM(0); }   // drain for final tile
        BAR();
    }

    // epilogue: 32x32 C/D layout col=lane&31, row=(reg&3)+8*(reg>>2)+4*(lane>>5)
    // (m74/m101-verified); ni-inner -> 2x128B contiguous segments per store
    float bv[2];
    #pragma unroll
    for (int ni = 0; ni < 2; ++ni) bv[ni] = bias[bn + wn + ni * 32 + l31];
    #pragma unroll
    for (int mi = 0; mi < 4; ++mi) {
        #pragma unroll
        for (int r = 0; r < 16; ++r) {
            const int row = bm + wm + mi * 32 + (r & 3) + 8 * (r >> 2) + 4 * lk;
            float* crow = C + (size_t)row * N + bn + wn + l31;
            crow[0]  = acc[mi][0][r] + bv[0];
            crow[32] = acc[mi][1][r] + bv[1];
        }
    }
#undef ST_A
#undef ST_B
#undef LDA32
#undef LDB32
#undef MFMA_HALF
}

extern "C" void kernel_launch(void* const* d_in, const int* in_sizes, int n_in,
                              void* d_out, int out_size, void* d_ws, size_t ws_size,
                              hipStream_t stream) {
    const float* x    = (const float*)d_in[0];
    const float* c0   = (const float*)d_in[1];
    const float* c1   = (const float*)d_in[2];
    const float* c2   = (const float*)d_in[3];
    const float* c3   = (const float*)d_in[4];
    const float* bias = (const float*)d_in[5];
    float* out = (float*)d_out;

    __bf16* xb = (__bf16*)d_ws;                    // 4096*1024 bf16 = 8.39 MB
    __bf16* wt = xb + (size_t)4096 * 1024;         // 4096*1024 bf16 = 8.39 MB

    prep<<<3072, 256, 0, stream>>>(x, xb, c0, c1, c2, c3, wt);
    tt_gemm<<<256, 512, 0, stream>>>(xb, wt, bias, out);
}